// Round 9
// baseline (441.664 us; speedup 1.0000x reference)
//
#include <hip/hip_runtime.h>

typedef unsigned short ushortT;
typedef short short8 __attribute__((ext_vector_type(8)));
typedef float floatx4 __attribute__((ext_vector_type(4)));

#define D_MODEL 2048
#define HEAD_DIM 128
#define NUM_HEADS 16
#define SEQ 2048
#define BATCH 2
#define M_TOK (BATCH * SEQ)                      // 4096 token rows
#define QKV_ELEMS ((size_t)M_TOK * D_MODEL)      // 8388608 elems per buffer
#define W_ELEMS ((size_t)D_MODEL * D_MODEL)      // 4194304 elems per weight

__device__ __forceinline__ float bf2f(ushortT h) {
    return __uint_as_float(((unsigned int)h) << 16);
}
__device__ __forceinline__ ushortT f2bf(float f) {
    unsigned int u = __float_as_uint(f);
    u = u + 0x7fffu + ((u >> 16) & 1u);   // round-to-nearest-even
    return (ushortT)(u >> 16);
}

// async global->LDS, 16B per lane. LDS dest = wave-uniform base + lane*16.
__device__ __forceinline__ void gload_lds16(const ushortT* g, short* lds_wave_base) {
    __builtin_amdgcn_global_load_lds(
        (const __attribute__((address_space(1))) unsigned int*)g,
        (__attribute__((address_space(3))) unsigned int*)lds_wave_base,
        16, 0, 0);
}

// ---------------------------------------------------------------------------
// One-shot fp32 -> bf16 conversion of x, Wq, Wk, Wv, Wo (fused, vectorized).
// ---------------------------------------------------------------------------
__global__ __launch_bounds__(256) void cvt_all(
    const float* __restrict__ x,  const float* __restrict__ wq,
    const float* __restrict__ wk, const float* __restrict__ wv,
    const float* __restrict__ wo,
    ushortT* __restrict__ xb,  ushortT* __restrict__ wqb,
    ushortT* __restrict__ wkb, ushortT* __restrict__ wvb,
    ushortT* __restrict__ wob)
{
    const size_t XC = QKV_ELEMS / 8;   // 1048576 chunks
    const size_t WC = W_ELEMS / 8;     // 524288 chunks
    size_t c = (size_t)blockIdx.x * 256 + threadIdx.x;
    const float* s; ushortT* d;
    if (c < XC)              { s = x;  d = xb;  }
    else if ((c -= XC) < WC) { s = wq; d = wqb; }
    else if ((c -= WC) < WC) { s = wk; d = wkb; }
    else if ((c -= WC) < WC) { s = wv; d = wvb; }
    else     { c -= WC;        s = wo; d = wob; }
    const float* f = s + c * 8;
    floatx4 a = *(const floatx4*)f;
    floatx4 b = *(const floatx4*)(f + 4);
    short8 r;
    r[0] = (short)f2bf(a.x); r[1] = (short)f2bf(a.y);
    r[2] = (short)f2bf(a.z); r[3] = (short)f2bf(a.w);
    r[4] = (short)f2bf(b.x); r[5] = (short)f2bf(b.y);
    r[6] = (short)f2bf(b.z); r[7] = (short)f2bf(b.w);
    *(short8*)(d + c * 8) = r;
}

// ---------------------------------------------------------------------------
// m97-structure bf16 GEMM, BK=64: C[M x 2048] = A @ W^T (+bias).
// 128x128 tile, 4 waves 2x2 (64x64 each, 4x4 MFMA frags). Same 2-barrier
// schedule as the verified BK=32 version, but half the barrier count.
// BK=64 rows are 256B, which would be a 16-way bank conflict; fixed with the
// R5-verified swizzle pair (rule 21): LDS stays linear, the GLOBAL source col
// is pre-swizzled (scol ^ (srow&7)<<3) and the ds_read col applies the same
// XOR ((lr&7)<<3) -> conflict-free by construction (R5 measured conflicts=0).
// VFRAG: for z==2 (V projection) the epilogue writes directly into the
// pre-packed vf fragment layout (replaces the vpack kernel; index map
// verified element-wise against vpack).
// ---------------------------------------------------------------------------
template<bool OUTF32, bool VFRAG>
__global__ __launch_bounds__(256) void gemm_bt(
    const ushortT* __restrict__ A,
    const ushortT* __restrict__ W0, const ushortT* __restrict__ W1,
    const ushortT* __restrict__ W2,
    void* C0, void* C1, void* C2, const float* __restrict__ bias)
{
    __shared__ short As[128 * 64];   // 16 KB
    __shared__ short Bs[128 * 64];   // 16 KB

    const int z = blockIdx.z;
    const ushortT* W = (z == 0) ? W0 : (z == 1 ? W1 : W2);
    void* C = (z == 0) ? C0 : (z == 1 ? C1 : C2);

    const int tid  = threadIdx.x;
    const int wave = tid >> 6;
    const int lane = tid & 63;
    const int lr   = lane & 15;
    const int quad = lane >> 4;
    const int wm   = (wave & 1) * 64;
    const int wn   = (wave >> 1) * 64;

    const int blockM = blockIdx.y * 128;
    const int blockN = blockIdx.x * 128;

    // staging map: per issue 32 rows x 64 cols; thread -> (srow, scol)
    const int srow = tid >> 3;                    // 0..31
    const int scol = (tid & 7) * 8;               // 0..56
    const int scolSwz = scol ^ ((srow & 7) << 3); // pre-swizzled source col
    const ushortT* ag = A + (size_t)(blockM + srow) * D_MODEL + scolSwz;
    const ushortT* wg = W + (size_t)(blockN + srow) * D_MODEL + scolSwz;
    short* al = As + wave * 512;   // wave-uniform LDS base (lane*16B implicit)
    short* bl = Bs + wave * 512;

    const int rswz = (lr & 7) << 3;               // read-side XOR (shorts)

    floatx4 acc[4][4];
    #pragma unroll
    for (int i = 0; i < 4; i++)
        #pragma unroll
        for (int j = 0; j < 4; j++) acc[i][j] = (floatx4){0.f, 0.f, 0.f, 0.f};

    for (int kk = 0; kk < D_MODEL; kk += 64) {
        #pragma unroll
        for (int i = 0; i < 4; i++) {
            gload_lds16(ag + kk + (size_t)(i * 32) * D_MODEL, al + i * 2048);
            gload_lds16(wg + kk + (size_t)(i * 32) * D_MODEL, bl + i * 2048);
        }
        __syncthreads();

        #pragma unroll
        for (int kh = 0; kh < 2; kh++) {
            const int cbase = (kh * 32 + quad * 8) ^ rswz;
            short8 af[4], bf[4];
            #pragma unroll
            for (int s = 0; s < 4; s++) {
                af[s] = *(const short8*)&As[(wm + s * 16 + lr) * 64 + cbase];
                bf[s] = *(const short8*)&Bs[(wn + s * 16 + lr) * 64 + cbase];
            }
            #pragma unroll
            for (int sm = 0; sm < 4; sm++)
                #pragma unroll
                for (int sn = 0; sn < 4; sn++)
                    acc[sm][sn] = __builtin_amdgcn_mfma_f32_16x16x32_bf16(
                        af[sm], bf[sn], acc[sm][sn], 0, 0, 0);
        }
        __syncthreads();
    }

    #pragma unroll
    for (int sm = 0; sm < 4; sm++) {
        const int row0 = blockM + wm + sm * 16 + quad * 4;
        #pragma unroll
        for (int sn = 0; sn < 4; sn++) {
            const int col = blockN + wn + sn * 16 + lr;
            const float bval = bias ? bias[col] : 0.f;
            #pragma unroll
            for (int rr = 0; rr < 4; rr++) {
                const float val = acc[sm][sn][rr] + bval;
                const int row = row0 + rr;
                if (VFRAG && z == 2) {
                    // direct-to-vf write (replaces vpack):
                    // t = row & 2047, b = row >> 11, h = col >> 7, d = col & 127
                    const int tt = row & (SEQ - 1);
                    const int bh2 = ((row >> 11) << 4) | (col >> 7);
                    const int dd = col & 127;
                    const size_t idx =
                        ((size_t)(bh2 * 8 + (dd >> 4)) * 64 + (tt >> 5)) * 512 +
                        (size_t)((((tt & 31) >> 3) * 16 + (dd & 15)) * 8 + (tt & 7));
                    ((ushortT*)C)[idx] = f2bf(val);
                } else if constexpr (OUTF32) {
                    ((float*)C)[(size_t)row * D_MODEL + col] = val;
                } else {
                    ((ushortT*)C)[(size_t)row * D_MODEL + col] = f2bf(val);
                }
            }
        }
    }
}

// ---------------------------------------------------------------------------
// K fragment pre-pack WITH FUSED RoPE (replaces rope-K + old kpack):
// kf[((bh*128 + kt16)*4 + ks)*512 + lane*8 + j]
//   = rope(K)[b, t = kt16*16 + lr, h, d = ks*32 + quad*8 + j]
// rope(K)[d<64]  = K[2d]*cos(t*theta[d])   - K[2d+1]*sin(t*theta[d])
// rope(K)[d>=64] = K[2(d-64)]*sin(...)     + K[2(d-64)+1]*cos(...)
// The 8 output d's per thread sit on one side of 64 (d0 multiple of 8), so
// inputs are 16 contiguous shorts. fp32 math, single bf16 rounding.
// ---------------------------------------------------------------------------
__global__ __launch_bounds__(256) void kpack_kernel(
    const ushortT* __restrict__ k, ushortT* __restrict__ kf,
    const float* __restrict__ theta)
{
    const int kt16 = blockIdx.x;     // 0..127
    const int bh   = blockIdx.y;     // 0..31
    const int b = bh >> 4, h = bh & 15;
    const int tid = threadIdx.x;
    const int ks = tid >> 6, lane = tid & 63;
    const int lr = lane & 15, quad = lane >> 4;

    const int t   = kt16 * 16 + lr;
    const int d0  = ks * 32 + quad * 8;
    const int dd0 = d0 & 63;
    const ushortT* src = k + (size_t)(b * SEQ + t) * D_MODEL + h * HEAD_DIM;
    short8 a  = *(const short8*)(src + 2 * dd0);
    short8 b8 = *(const short8*)(src + 2 * dd0 + 8);
    const float tp = (float)t;

    short8 v;
    #pragma unroll
    for (int j = 0; j < 8; j++) {
        const float ve = bf2f((ushortT)(j < 4 ? a[2 * j]     : b8[2 * j - 8]));
        const float vo = bf2f((ushortT)(j < 4 ? a[2 * j + 1] : b8[2 * j - 7]));
        const float ang = tp * theta[dd0 + j];
        const float s = sinf(ang), c = cosf(ang);
        v[j] = (short)f2bf((d0 < 64) ? (ve * c - vo * s) : (ve * s + vo * c));
    }
    *(short8*)(kf + ((size_t)(bh * 128 + kt16) * 4 + ks) * 512 + lane * 8) = v;
}

// ---------------------------------------------------------------------------
// MFMA flash attention (R7-verified structure: double-buffered LDS K/V,
// max-free softmax, ones-MFMA row sums) with FUSED RoPE-Q: the Qf build reads
// raw projected q and applies rope in fp32 (replaces rope-Q; one bf16
// rounding less than before). Once per pass, ~32 trig pairs/thread.
// XCD remap: xcd = lid&7 owns heads {xcd, xcd+8, xcd+16, xcd+24}.
// ---------------------------------------------------------------------------
__global__ __launch_bounds__(256) void flash_attn2(
    const ushortT* __restrict__ q, const ushortT* __restrict__ kf,
    const ushortT* __restrict__ vf, ushortT* __restrict__ ctx,
    const float* __restrict__ theta)
{
    __shared__ short Kt[2][16 * 512];    // 2 x 16 KB
    __shared__ short Vt[2][16 * 512];    // 2 x 16 KB
    __shared__ short Pl[4][16][72];      // per-wave P transpose buffer (9.2 KB)

    const unsigned lid = blockIdx.x;     // 0..511
    const int xcd  = lid & 7;
    const int slot = lid >> 3;           // 0..63
    const int ih   = slot >> 4;          // 0..3
    const int qtb  = slot & 15;          // 0..15
    const int bh   = (ih << 3) | xcd;    // head group pinned to one XCD

    const int b = bh >> 4, h = bh & 15;
    const size_t base = (size_t)b * SEQ * D_MODEL + h * HEAD_DIM;
    const size_t kfb = (size_t)bh * 128 * 4 * 512;
    const size_t vfb = (size_t)bh * 8 * 64 * 512;
    const int tid = threadIdx.x;
    const int w = tid >> 6, lane = tid & 63;
    const int lr = lane & 15, quad = lane >> 4;
    short* myP = &Pl[w][0][0];

    // constant all-ones bf16 B-frag for the row-sum MFMA
    short8 onesf;
    #pragma unroll
    for (int j = 0; j < 8; j++) onesf[j] = (short)0x3F80;   // bf16 1.0

    // stage k-tile kt0 into buffer buf (8 gload_lds16 per thread)
    auto stage_tile = [&](int kt0, int buf) {
        const ushortT* ksrc = kf + kfb + (size_t)kt0 * 128;
        #pragma unroll
        for (int c = 0; c < 4; c++)
            gload_lds16(ksrc + c * 2048 + tid * 8, &Kt[buf][c * 2048 + w * 512]);
        #pragma unroll
        for (int c = 0; c < 4; c++) {
            const int e    = c * 2048 + tid * 8;
            const int dsub = e >> 10;
            const int rem  = e & 1023;
            const ushortT* vsrc = vf + vfb +
                ((size_t)dsub * 64 + (kt0 >> 5) + (rem >> 9)) * 512 + (rem & 511);
            gload_lds16(vsrc, &Vt[buf][c * 2048 + w * 512]);
        }
    };

    for (int pass = 0; pass < 2; pass++) {
        const int qt = (pass == 0) ? qtb : (SEQ / 64 - 1 - qtb);
        const int q0 = qt * 64 + w * 16;

        // Q A-frags: fused RoPE + 1/sqrt(HD), single bf16 rounding
        short8 Qf[4];
        {
            const ushortT* qrow = q + base + (size_t)(q0 + lr) * D_MODEL;
            const float tp = (float)(q0 + lr);
            #pragma unroll
            for (int ks = 0; ks < 4; ks++) {
                const int d0  = ks * 32 + quad * 8;
                const int dd0 = d0 & 63;
                short8 a  = *(const short8*)(qrow + 2 * dd0);
                short8 b8 = *(const short8*)(qrow + 2 * dd0 + 8);
                #pragma unroll
                for (int j = 0; j < 8; j++) {
                    const float ve = bf2f((ushortT)(j < 4 ? a[2 * j]     : b8[2 * j - 8]));
                    const float vo = bf2f((ushortT)(j < 4 ? a[2 * j + 1] : b8[2 * j - 7]));
                    const float ang = tp * theta[dd0 + j];
                    const float s = sinf(ang), c = cosf(ang);
                    const float r = (d0 < 64) ? (ve * c - vo * s) : (ve * s + vo * c);
                    Qf[ks][j] = (short)f2bf(r * 0.08838834764831845f);
                }
            }
        }

        floatx4 Of[8];
        #pragma unroll
        for (int i = 0; i < 8; i++) Of[i] = (floatx4){0.f, 0.f, 0.f, 0.f};
        floatx4 lacc = (floatx4){0.f, 0.f, 0.f, 0.f};   // row sums via ones-MFMA

        // prologue: stage tile 0, certify, publish
        stage_tile(0, 0);
        asm volatile("s_waitcnt vmcnt(0)" ::: "memory");
        __builtin_amdgcn_s_barrier();
        asm volatile("" ::: "memory");

        const int ntiles = qt + 1;
        for (int t = 0; t < ntiles; ++t) {
            const int buf = t & 1;
            const int kt0 = t * 64;

            // --- S = Q K^T from LDS K frags ---
            floatx4 Sf[4];
            #pragma unroll
            for (int sub = 0; sub < 4; sub++) {
                floatx4 acc = {0.f, 0.f, 0.f, 0.f};
                #pragma unroll
                for (int ks = 0; ks < 4; ks++) {
                    short8 Kf_ = *(const short8*)(&Kt[buf][(sub * 4 + ks) * 512 + lane * 8]);
                    acc = __builtin_amdgcn_mfma_f32_16x16x32_bf16(Qf[ks], Kf_, acc, 0, 0, 0);
                }
                Sf[sub] = acc;
            }

            // --- causal mask (diagonal tile only) ---
            if (kt0 == qt * 64) {
                #pragma unroll
                for (int sub = 0; sub < 4; sub++) {
                    const int ktg = kt0 + sub * 16 + lr;
                    #pragma unroll
                    for (int i = 0; i < 4; i++)
                        if (ktg > q0 + quad * 4 + i) Sf[sub][i] = -1e30f;
                }
            }

            // --- max-free softmax: P = exp(min(S, 60)), write to P buffer ---
            #pragma unroll
            for (int sub = 0; sub < 4; sub++) {
                #pragma unroll
                for (int i = 0; i < 4; i++) {
                    const float p = __expf(fminf(Sf[sub][i], 60.f));
                    myP[(quad * 4 + i) * 72 + sub * 16 + lr] = (short)f2bf(p);
                }
            }

            // --- V frags into regs (issued now; covers the P-write latency) ---
            short8 Vr[16];
            #pragma unroll
            for (int dsub = 0; dsub < 8; dsub++) {
                Vr[2 * dsub]     = *(const short8*)(&Vt[buf][dsub * 1024 + lane * 8]);
                Vr[2 * dsub + 1] = *(const short8*)(&Vt[buf][dsub * 1024 + 512 + lane * 8]);
            }

            // --- issue next tile's staging (hides under PV) ---
            if (t + 1 < ntiles) stage_tile((t + 1) * 64, buf ^ 1);

            // --- P: C-layout -> A-layout via wave-private LDS ---
            asm volatile("s_waitcnt lgkmcnt(0)" ::: "memory");
            short8 Pf0 = *(const short8*)(myP + lr * 72 + quad * 8);
            short8 Pf1 = *(const short8*)(myP + lr * 72 + 32 + quad * 8);

            // --- row sums: lacc += P . 1 (two ones-MFMAs) ---
            lacc = __builtin_amdgcn_mfma_f32_16x16x32_bf16(Pf0, onesf, lacc, 0, 0, 0);
            lacc = __builtin_amdgcn_mfma_f32_16x16x32_bf16(Pf1, onesf, lacc, 0, 0, 0);

            // --- O += P V (V already in registers) ---
            #pragma unroll
            for (int dsub = 0; dsub < 8; dsub++) {
                Of[dsub] = __builtin_amdgcn_mfma_f32_16x16x32_bf16(
                    Pf0, Vr[2 * dsub], Of[dsub], 0, 0, 0);
                Of[dsub] = __builtin_amdgcn_mfma_f32_16x16x32_bf16(
                    Pf1, Vr[2 * dsub + 1], Of[dsub], 0, 0, 0);
            }

            // --- tile boundary: certify own staging loads, publish ---
            asm volatile("s_waitcnt vmcnt(0)" ::: "memory");
            __builtin_amdgcn_s_barrier();
            asm volatile("" ::: "memory");
        }

        // --- epilogue ---
        float inv[4];
        #pragma unroll
        for (int i = 0; i < 4; i++) inv[i] = 1.f / lacc[i];
        #pragma unroll
        for (int dsub = 0; dsub < 8; dsub++)
            #pragma unroll
            for (int i = 0; i < 4; i++)
                ctx[base + (size_t)(q0 + quad * 4 + i) * D_MODEL + dsub * 16 + lr] =
                    f2bf(Of[dsub][i] * inv[i]);
    }
}

// ---------------------------------------------------------------------------
extern "C" void kernel_launch(void* const* d_in, const int* in_sizes, int n_in,
                              void* d_out, int out_size, void* d_ws, size_t ws_size,
                              hipStream_t stream) {
    const float* x     = (const float*)d_in[0];
    const float* Wq    = (const float*)d_in[1];
    const float* Wk    = (const float*)d_in[2];
    const float* Wv    = (const float*)d_in[3];
    const float* Wo    = (const float*)d_in[4];
    const float* bo    = (const float*)d_in[5];
    const float* theta = (const float*)d_in[6];

    // Workspace (shorts), total 96 MiB:
    //   qb | kb | vfb | kfb(/xb) | wqb | wkb | wvb | wob
    // ctx overlays wqb+wkb (both dead after the QKV gemm; 2*W_ELEMS == QKV_ELEMS).
    ushortT* ws  = (ushortT*)d_ws;
    ushortT* qb   = ws;                      // Q (bf16, raw: rope fused in attn)
    ushortT* kb   = ws + QKV_ELEMS;          // K (raw; rope fused in kpack)
    ushortT* vfb  = ws + 2 * QKV_ELEMS;      // V frags (written by gemm epilogue)
    ushortT* kfbp = ws + 3 * QKV_ELEMS;      // K frags (xb before kpack)
    ushortT* xb   = kfbp;                    // bf16 x (dead after QKV gemm)
    ushortT* wqb  = ws + 4 * QKV_ELEMS;      // bf16 weights
    ushortT* wkb  = wqb + W_ELEMS;
    ushortT* wvb  = wkb + W_ELEMS;
    ushortT* wob  = wvb + W_ELEMS;
    ushortT* ctx  = wqb;                     // overlays wqb+wkb after QKV gemm

    // 0. fp32 -> bf16 one-shot conversion of x and all weights
    cvt_all<<<dim3((unsigned)((QKV_ELEMS / 8 + 4 * (W_ELEMS / 8)) / 256)), 256, 0, stream>>>(
        x, Wq, Wk, Wv, Wo, xb, wqb, wkb, wvb, wob);

    // 1. QKV projections: Q->qb, K->kb (row-major), V->vfb (frag layout, fused)
    gemm_bt<false, true><<<dim3(D_MODEL / 128, M_TOK / 128, 3), 256, 0, stream>>>(
        xb, wqb, wkb, wvb, qb, kb, vfb, nullptr);

    // 2. K fragment pack with fused RoPE: kb -> kfb (overlays dead xb)
    kpack_kernel<<<dim3(SEQ / 16, BATCH * NUM_HEADS), 256, 0, stream>>>(kb, kfbp, theta);

    // 3. Flash attention (fused RoPE-Q, max-free softmax) -> ctx
    flash_attn2<<<dim3(512), 256, 0, stream>>>(qb, kfbp, vfb, ctx, theta);

    // 4. Output projection + bias (bf16 in, fp32 out)
    gemm_bt<true, false><<<dim3(D_MODEL / 128, M_TOK / 128, 1), 256, 0, stream>>>(
        ctx, wob, wob, wob, d_out, d_out, d_out, bo);
}

// Round 10
// 412.664 us; speedup vs baseline: 1.0703x; 1.0703x over previous
//
#include <hip/hip_runtime.h>

typedef unsigned short ushortT;
typedef short short8 __attribute__((ext_vector_type(8)));
typedef short short4v __attribute__((ext_vector_type(4)));
typedef float floatx4 __attribute__((ext_vector_type(4)));

#define D_MODEL 2048
#define HEAD_DIM 128
#define NUM_HEADS 16
#define SEQ 2048
#define BATCH 2
#define M_TOK (BATCH * SEQ)                      // 4096 token rows
#define QKV_ELEMS ((size_t)M_TOK * D_MODEL)      // 8388608 elems per buffer
#define W_ELEMS ((size_t)D_MODEL * D_MODEL)      // 4194304 elems per weight

__device__ __forceinline__ float bf2f(ushortT h) {
    return __uint_as_float(((unsigned int)h) << 16);
}
__device__ __forceinline__ ushortT f2bf(float f) {
    unsigned int u = __float_as_uint(f);
    u = u + 0x7fffu + ((u >> 16) & 1u);   // round-to-nearest-even
    return (ushortT)(u >> 16);
}

// async global->LDS, 16B per lane. LDS dest = wave-uniform base + lane*16.
__device__ __forceinline__ void gload_lds16(const ushortT* g, short* lds_wave_base) {
    __builtin_amdgcn_global_load_lds(
        (const __attribute__((address_space(1))) unsigned int*)g,
        (__attribute__((address_space(3))) unsigned int*)lds_wave_base,
        16, 0, 0);
}

// ---------------------------------------------------------------------------
// One-shot fp32 -> bf16 conversion of x, Wq, Wk, Wv, Wo (fused, vectorized).
// ---------------------------------------------------------------------------
__global__ __launch_bounds__(256) void cvt_all(
    const float* __restrict__ x,  const float* __restrict__ wq,
    const float* __restrict__ wk, const float* __restrict__ wv,
    const float* __restrict__ wo,
    ushortT* __restrict__ xb,  ushortT* __restrict__ wqb,
    ushortT* __restrict__ wkb, ushortT* __restrict__ wvb,
    ushortT* __restrict__ wob)
{
    const size_t XC = QKV_ELEMS / 8;   // 1048576 chunks
    const size_t WC = W_ELEMS / 8;     // 524288 chunks
    size_t c = (size_t)blockIdx.x * 256 + threadIdx.x;
    const float* s; ushortT* d;
    if (c < XC)              { s = x;  d = xb;  }
    else if ((c -= XC) < WC) { s = wq; d = wqb; }
    else if ((c -= WC) < WC) { s = wk; d = wkb; }
    else if ((c -= WC) < WC) { s = wv; d = wvb; }
    else     { c -= WC;        s = wo; d = wob; }
    const float* f = s + c * 8;
    floatx4 a = *(const floatx4*)f;
    floatx4 b = *(const floatx4*)(f + 4);
    short8 r;
    r[0] = (short)f2bf(a.x); r[1] = (short)f2bf(a.y);
    r[2] = (short)f2bf(a.z); r[3] = (short)f2bf(a.w);
    r[4] = (short)f2bf(b.x); r[5] = (short)f2bf(b.y);
    r[6] = (short)f2bf(b.z); r[7] = (short)f2bf(b.w);
    *(short8*)(d + c * 8) = r;
}

// ---------------------------------------------------------------------------
// sin/cos table: tbl[(t*64+d)*2] = sin(t*theta[d]), +1 = cos.  1 MB, L2-fit.
// Computed ONCE (131K trig pairs) instead of per-consumer (16.8M pairs --
// the R8 regression). Placed in the dead wvb region after the QKV gemm.
// ---------------------------------------------------------------------------
__global__ __launch_bounds__(256) void sincos_kernel(
    float* __restrict__ tbl, const float* __restrict__ theta)
{
    const int p = blockIdx.x * 256 + threadIdx.x;   // 0..131071
    const int t = p >> 6, d = p & 63;
    const float ang = (float)t * theta[d];
    tbl[2 * p]     = sinf(ang);
    tbl[2 * p + 1] = cosf(ang);
}

// ---------------------------------------------------------------------------
// m97-structure bf16 GEMM (R4/R6-verified, 792 TF): C[M x 2048] = A@W^T (+bias).
// 128x128 tile, 4 waves 2x2 (64x64 each, 4x4 MFMA frags), BK=32.
// Linear [128][32] LDS filled by global_load_lds width-16.
// VFRAG: for z==2 (V projection) the epilogue writes directly into the
// pre-packed vf fragment layout (replaces vpack; map HW-verified in R8).
// The 4 rr outputs are index-contiguous (tt&7 = quad*4+rr), stored as one
// 8B short4 instead of 4 scattered 2B stores.
// ---------------------------------------------------------------------------
template<bool OUTF32, bool VFRAG>
__global__ __launch_bounds__(256) void gemm_bt(
    const ushortT* __restrict__ A,
    const ushortT* __restrict__ W0, const ushortT* __restrict__ W1,
    const ushortT* __restrict__ W2,
    void* C0, void* C1, void* C2, const float* __restrict__ bias)
{
    __shared__ short As[128 * 32];
    __shared__ short Bs[128 * 32];

    const int z = blockIdx.z;
    const ushortT* W = (z == 0) ? W0 : (z == 1 ? W1 : W2);
    void* C = (z == 0) ? C0 : (z == 1 ? C1 : C2);

    const int tid  = threadIdx.x;
    const int wave = tid >> 6;
    const int lane = tid & 63;
    const int lr   = lane & 15;
    const int quad = lane >> 4;
    const int wm   = (wave & 1) * 64;
    const int wn   = (wave >> 1) * 64;

    const int blockM = blockIdx.y * 128;
    const int blockN = blockIdx.x * 128;

    const int srow = tid >> 2;          // staging row 0..63 (+64 chunk 1)
    const int scol = (tid & 3) * 8;
    const ushortT* ag = A + (size_t)(blockM + srow) * D_MODEL + scol;
    const ushortT* wg = W + (size_t)(blockN + srow) * D_MODEL + scol;
    short* al = As + wave * 512;        // wave-uniform LDS base
    short* bl = Bs + wave * 512;

    floatx4 acc[4][4];
    #pragma unroll
    for (int i = 0; i < 4; i++)
        #pragma unroll
        for (int j = 0; j < 4; j++) acc[i][j] = (floatx4){0.f, 0.f, 0.f, 0.f};

    for (int kk = 0; kk < D_MODEL; kk += 32) {
        gload_lds16(ag + kk,                 al);
        gload_lds16(ag + kk + 64 * D_MODEL,  al + 64 * 32);
        gload_lds16(wg + kk,                 bl);
        gload_lds16(wg + kk + 64 * D_MODEL,  bl + 64 * 32);
        __syncthreads();

        short8 af[4], bf[4];
        #pragma unroll
        for (int s = 0; s < 4; s++) {
            af[s] = *(const short8*)&As[(wm + s * 16 + lr) * 32 + quad * 8];
            bf[s] = *(const short8*)&Bs[(wn + s * 16 + lr) * 32 + quad * 8];
        }
        #pragma unroll
        for (int sm = 0; sm < 4; sm++)
            #pragma unroll
            for (int sn = 0; sn < 4; sn++)
                acc[sm][sn] = __builtin_amdgcn_mfma_f32_16x16x32_bf16(
                    af[sm], bf[sn], acc[sm][sn], 0, 0, 0);
        __syncthreads();
    }

    #pragma unroll
    for (int sm = 0; sm < 4; sm++) {
        const int row0 = blockM + wm + sm * 16 + quad * 4;
        #pragma unroll
        for (int sn = 0; sn < 4; sn++) {
            const int col = blockN + wn + sn * 16 + lr;
            const float bval = bias ? bias[col] : 0.f;
            if (VFRAG && z == 2) {
                // direct-to-vf write (replaces vpack; R8-HW-verified map).
                // rr 0..3 are contiguous in idx (tt&7 = quad*4+rr stays in
                // one 8-slot) -> single short4 store.
                const int tt0 = row0 & (SEQ - 1);
                const int bh2 = ((row0 >> 11) << 4) | (col >> 7);
                const int dd  = col & 127;
                short4v v4;
                #pragma unroll
                for (int rr = 0; rr < 4; rr++)
                    v4[rr] = (short)f2bf(acc[sm][sn][rr]);
                const size_t idx0 =
                    ((size_t)(bh2 * 8 + (dd >> 4)) * 64 + (tt0 >> 5)) * 512 +
                    (size_t)((((tt0 & 31) >> 3) * 16 + (dd & 15)) * 8 + (tt0 & 7));
                *(short4v*)((ushortT*)C + idx0) = v4;
            } else {
                #pragma unroll
                for (int rr = 0; rr < 4; rr++) {
                    const float val = acc[sm][sn][rr] + bval;
                    if constexpr (OUTF32)
                        ((float*)C)[(size_t)(row0 + rr) * D_MODEL + col] = val;
                    else
                        ((ushortT*)C)[(size_t)(row0 + rr) * D_MODEL + col] = f2bf(val);
                }
            }
        }
    }
}

// ---------------------------------------------------------------------------
// K fragment pre-pack WITH FUSED RoPE (table-driven):
// kf[((bh*128 + kt16)*4 + ks)*512 + lane*8 + j]
//   = rope(K)[b, t = kt16*16 + lr, h, d = ks*32 + quad*8 + j]
// sin/cos from the precomputed table (16 contiguous floats per thread).
// ---------------------------------------------------------------------------
__global__ __launch_bounds__(256) void kpack_kernel(
    const ushortT* __restrict__ k, ushortT* __restrict__ kf,
    const float* __restrict__ tbl)
{
    const int kt16 = blockIdx.x;     // 0..127
    const int bh   = blockIdx.y;     // 0..31
    const int b = bh >> 4, h = bh & 15;
    const int tid = threadIdx.x;
    const int ks = tid >> 6, lane = tid & 63;
    const int lr = lane & 15, quad = lane >> 4;

    const int t   = kt16 * 16 + lr;
    const int d0  = ks * 32 + quad * 8;
    const int dd0 = d0 & 63;
    const ushortT* src = k + (size_t)(b * SEQ + t) * D_MODEL + h * HEAD_DIM;
    short8 a  = *(const short8*)(src + 2 * dd0);
    short8 b8 = *(const short8*)(src + 2 * dd0 + 8);
    const float* tb = tbl + 2 * ((size_t)t * 64 + dd0);

    short8 v;
    #pragma unroll
    for (int j = 0; j < 8; j++) {
        const float ve = bf2f((ushortT)(j < 4 ? a[2 * j]     : b8[2 * j - 8]));
        const float vo = bf2f((ushortT)(j < 4 ? a[2 * j + 1] : b8[2 * j - 7]));
        const float s = tb[2 * j], c = tb[2 * j + 1];
        v[j] = (short)f2bf((d0 < 64) ? (ve * c - vo * s) : (ve * s + vo * c));
    }
    *(short8*)(kf + ((size_t)(bh * 128 + kt16) * 4 + ks) * 512 + lane * 8) = v;
}

// ---------------------------------------------------------------------------
// MFMA flash attention (R7-verified structure: double-buffered LDS K/V,
// max-free softmax, ones-MFMA row sums) with table-driven fused RoPE-Q.
// XCD remap: xcd = lid&7 owns heads {xcd, xcd+8, xcd+16, xcd+24}.
// ---------------------------------------------------------------------------
__global__ __launch_bounds__(256) void flash_attn2(
    const ushortT* __restrict__ q, const ushortT* __restrict__ kf,
    const ushortT* __restrict__ vf, ushortT* __restrict__ ctx,
    const float* __restrict__ tbl)
{
    __shared__ short Kt[2][16 * 512];    // 2 x 16 KB
    __shared__ short Vt[2][16 * 512];    // 2 x 16 KB
    __shared__ short Pl[4][16][72];      // per-wave P transpose buffer (9.2 KB)

    const unsigned lid = blockIdx.x;     // 0..511
    const int xcd  = lid & 7;
    const int slot = lid >> 3;           // 0..63
    const int ih   = slot >> 4;          // 0..3
    const int qtb  = slot & 15;          // 0..15
    const int bh   = (ih << 3) | xcd;    // head group pinned to one XCD

    const int b = bh >> 4, h = bh & 15;
    const size_t base = (size_t)b * SEQ * D_MODEL + h * HEAD_DIM;
    const size_t kfb = (size_t)bh * 128 * 4 * 512;
    const size_t vfb = (size_t)bh * 8 * 64 * 512;
    const int tid = threadIdx.x;
    const int w = tid >> 6, lane = tid & 63;
    const int lr = lane & 15, quad = lane >> 4;
    short* myP = &Pl[w][0][0];

    // constant all-ones bf16 B-frag for the row-sum MFMA
    short8 onesf;
    #pragma unroll
    for (int j = 0; j < 8; j++) onesf[j] = (short)0x3F80;   // bf16 1.0

    // stage k-tile kt0 into buffer buf (8 gload_lds16 per thread)
    auto stage_tile = [&](int kt0, int buf) {
        const ushortT* ksrc = kf + kfb + (size_t)kt0 * 128;
        #pragma unroll
        for (int c = 0; c < 4; c++)
            gload_lds16(ksrc + c * 2048 + tid * 8, &Kt[buf][c * 2048 + w * 512]);
        #pragma unroll
        for (int c = 0; c < 4; c++) {
            const int e    = c * 2048 + tid * 8;
            const int dsub = e >> 10;
            const int rem  = e & 1023;
            const ushortT* vsrc = vf + vfb +
                ((size_t)dsub * 64 + (kt0 >> 5) + (rem >> 9)) * 512 + (rem & 511);
            gload_lds16(vsrc, &Vt[buf][c * 2048 + w * 512]);
        }
    };

    for (int pass = 0; pass < 2; pass++) {
        const int qt = (pass == 0) ? qtb : (SEQ / 64 - 1 - qtb);
        const int q0 = qt * 64 + w * 16;

        // Q A-frags: table-driven RoPE + 1/sqrt(HD), single bf16 rounding
        short8 Qf[4];
        {
            const ushortT* qrow = q + base + (size_t)(q0 + lr) * D_MODEL;
            const float* trow = tbl + 2 * ((size_t)(q0 + lr) * 64);
            #pragma unroll
            for (int ks = 0; ks < 4; ks++) {
                const int d0  = ks * 32 + quad * 8;
                const int dd0 = d0 & 63;
                short8 a  = *(const short8*)(qrow + 2 * dd0);
                short8 b8 = *(const short8*)(qrow + 2 * dd0 + 8);
                const float* tb = trow + 2 * dd0;
                #pragma unroll
                for (int j = 0; j < 8; j++) {
                    const float ve = bf2f((ushortT)(j < 4 ? a[2 * j]     : b8[2 * j - 8]));
                    const float vo = bf2f((ushortT)(j < 4 ? a[2 * j + 1] : b8[2 * j - 7]));
                    const float s = tb[2 * j], c = tb[2 * j + 1];
                    const float r = (d0 < 64) ? (ve * c - vo * s) : (ve * s + vo * c);
                    Qf[ks][j] = (short)f2bf(r * 0.08838834764831845f);
                }
            }
        }

        floatx4 Of[8];
        #pragma unroll
        for (int i = 0; i < 8; i++) Of[i] = (floatx4){0.f, 0.f, 0.f, 0.f};
        floatx4 lacc = (floatx4){0.f, 0.f, 0.f, 0.f};   // row sums via ones-MFMA

        // prologue: stage tile 0, certify, publish
        stage_tile(0, 0);
        asm volatile("s_waitcnt vmcnt(0)" ::: "memory");
        __builtin_amdgcn_s_barrier();
        asm volatile("" ::: "memory");

        const int ntiles = qt + 1;
        for (int t = 0; t < ntiles; ++t) {
            const int buf = t & 1;
            const int kt0 = t * 64;

            // --- S = Q K^T from LDS K frags ---
            floatx4 Sf[4];
            #pragma unroll
            for (int sub = 0; sub < 4; sub++) {
                floatx4 acc = {0.f, 0.f, 0.f, 0.f};
                #pragma unroll
                for (int ks = 0; ks < 4; ks++) {
                    short8 Kf_ = *(const short8*)(&Kt[buf][(sub * 4 + ks) * 512 + lane * 8]);
                    acc = __builtin_amdgcn_mfma_f32_16x16x32_bf16(Qf[ks], Kf_, acc, 0, 0, 0);
                }
                Sf[sub] = acc;
            }

            // --- causal mask (diagonal tile only) ---
            if (kt0 == qt * 64) {
                #pragma unroll
                for (int sub = 0; sub < 4; sub++) {
                    const int ktg = kt0 + sub * 16 + lr;
                    #pragma unroll
                    for (int i = 0; i < 4; i++)
                        if (ktg > q0 + quad * 4 + i) Sf[sub][i] = -1e30f;
                }
            }

            // --- max-free softmax: P = exp(min(S, 60)), write to P buffer ---
            #pragma unroll
            for (int sub = 0; sub < 4; sub++) {
                #pragma unroll
                for (int i = 0; i < 4; i++) {
                    const float p = __expf(fminf(Sf[sub][i], 60.f));
                    myP[(quad * 4 + i) * 72 + sub * 16 + lr] = (short)f2bf(p);
                }
            }

            // --- V frags into regs (issued now; covers the P-write latency) ---
            short8 Vr[16];
            #pragma unroll
            for (int dsub = 0; dsub < 8; dsub++) {
                Vr[2 * dsub]     = *(const short8*)(&Vt[buf][dsub * 1024 + lane * 8]);
                Vr[2 * dsub + 1] = *(const short8*)(&Vt[buf][dsub * 1024 + 512 + lane * 8]);
            }

            // --- issue next tile's staging (hides under PV) ---
            if (t + 1 < ntiles) stage_tile((t + 1) * 64, buf ^ 1);

            // --- P: C-layout -> A-layout via wave-private LDS ---
            asm volatile("s_waitcnt lgkmcnt(0)" ::: "memory");
            short8 Pf0 = *(const short8*)(myP + lr * 72 + quad * 8);
            short8 Pf1 = *(const short8*)(myP + lr * 72 + 32 + quad * 8);

            // --- row sums: lacc += P . 1 (two ones-MFMAs) ---
            lacc = __builtin_amdgcn_mfma_f32_16x16x32_bf16(Pf0, onesf, lacc, 0, 0, 0);
            lacc = __builtin_amdgcn_mfma_f32_16x16x32_bf16(Pf1, onesf, lacc, 0, 0, 0);

            // --- O += P V (V already in registers) ---
            #pragma unroll
            for (int dsub = 0; dsub < 8; dsub++) {
                Of[dsub] = __builtin_amdgcn_mfma_f32_16x16x32_bf16(
                    Pf0, Vr[2 * dsub], Of[dsub], 0, 0, 0);
                Of[dsub] = __builtin_amdgcn_mfma_f32_16x16x32_bf16(
                    Pf1, Vr[2 * dsub + 1], Of[dsub], 0, 0, 0);
            }

            // --- tile boundary: certify own staging loads, publish ---
            asm volatile("s_waitcnt vmcnt(0)" ::: "memory");
            __builtin_amdgcn_s_barrier();
            asm volatile("" ::: "memory");
        }

        // --- epilogue ---
        float inv[4];
        #pragma unroll
        for (int i = 0; i < 4; i++) inv[i] = 1.f / lacc[i];
        #pragma unroll
        for (int dsub = 0; dsub < 8; dsub++)
            #pragma unroll
            for (int i = 0; i < 4; i++)
                ctx[base + (size_t)(q0 + quad * 4 + i) * D_MODEL + dsub * 16 + lr] =
                    f2bf(Of[dsub][i] * inv[i]);
    }
}

// ---------------------------------------------------------------------------
extern "C" void kernel_launch(void* const* d_in, const int* in_sizes, int n_in,
                              void* d_out, int out_size, void* d_ws, size_t ws_size,
                              hipStream_t stream) {
    const float* x     = (const float*)d_in[0];
    const float* Wq    = (const float*)d_in[1];
    const float* Wk    = (const float*)d_in[2];
    const float* Wv    = (const float*)d_in[3];
    const float* Wo    = (const float*)d_in[4];
    const float* bo    = (const float*)d_in[5];
    const float* theta = (const float*)d_in[6];

    // Workspace (shorts), total 96 MiB:
    //   qb | kb | vfb | kfb(/xb) | wqb | wkb | wvb | wob
    // ctx overlays wqb+wkb (dead after QKV gemm); sin/cos table overlays wvb
    // (dead after QKV gemm; table = 0.5 MiB << W_ELEMS).
    ushortT* ws  = (ushortT*)d_ws;
    ushortT* qb   = ws;                      // Q (bf16, raw; rope fused in attn)
    ushortT* kb   = ws + QKV_ELEMS;          // K (raw; rope fused in kpack)
    ushortT* vfb  = ws + 2 * QKV_ELEMS;      // V frags (written by gemm epilogue)
    ushortT* kfbp = ws + 3 * QKV_ELEMS;      // K frags (xb before kpack)
    ushortT* xb   = kfbp;                    // bf16 x (dead after QKV gemm)
    ushortT* wqb  = ws + 4 * QKV_ELEMS;      // bf16 weights
    ushortT* wkb  = wqb + W_ELEMS;
    ushortT* wvb  = wkb + W_ELEMS;
    ushortT* wob  = wvb + W_ELEMS;
    ushortT* ctx  = wqb;                     // overlays wqb+wkb after QKV gemm
    float*   tbl  = (float*)wvb;             // overlays wvb after QKV gemm

    // 0. fp32 -> bf16 one-shot conversion of x and all weights
    cvt_all<<<dim3((unsigned)((QKV_ELEMS / 8 + 4 * (W_ELEMS / 8)) / 256)), 256, 0, stream>>>(
        x, Wq, Wk, Wv, Wo, xb, wqb, wkb, wvb, wob);

    // 1. QKV projections: Q->qb, K->kb (row-major), V->vfb (frag layout, fused)
    gemm_bt<false, true><<<dim3(D_MODEL / 128, M_TOK / 128, 3), 256, 0, stream>>>(
        xb, wqb, wkb, wvb, qb, kb, vfb, nullptr);

    // 2. sin/cos table (131K pairs, once) -> tbl (overlays dead wvb)
    sincos_kernel<<<dim3(SEQ * 64 / 256), 256, 0, stream>>>(tbl, theta);

    // 3. K fragment pack with table-driven RoPE: kb -> kfb (overlays dead xb)
    kpack_kernel<<<dim3(SEQ / 16, BATCH * NUM_HEADS), 256, 0, stream>>>(kb, kfbp, tbl);

    // 4. Flash attention (table-driven RoPE-Q, max-free softmax) -> ctx
    flash_attn2<<<dim3(512), 256, 0, stream>>>(qb, kfbp, vfb, ctx, tbl);

    // 5. Output projection + bias (bf16 in, fp32 out)
    gemm_bt<true, false><<<dim3(D_MODEL / 128, M_TOK / 128, 1), 256, 0, stream>>>(
        ctx, wob, wob, wob, d_out, d_out, d_out, bo);
}

// Round 11
// 400.358 us; speedup vs baseline: 1.1032x; 1.0307x over previous
//
#include <hip/hip_runtime.h>

typedef unsigned short ushortT;
typedef short short8 __attribute__((ext_vector_type(8)));
typedef float floatx4 __attribute__((ext_vector_type(4)));

#define D_MODEL 2048
#define HEAD_DIM 128
#define NUM_HEADS 16
#define SEQ 2048
#define BATCH 2
#define M_TOK (BATCH * SEQ)                      // 4096 token rows
#define QKV_ELEMS ((size_t)M_TOK * D_MODEL)      // 8388608 elems per buffer
#define W_ELEMS ((size_t)D_MODEL * D_MODEL)      // 4194304 elems per weight

__device__ __forceinline__ float bf2f(ushortT h) {
    return __uint_as_float(((unsigned int)h) << 16);
}
__device__ __forceinline__ ushortT f2bf(float f) {
    unsigned int u = __float_as_uint(f);
    u = u + 0x7fffu + ((u >> 16) & 1u);   // round-to-nearest-even
    return (ushortT)(u >> 16);
}

// async global->LDS, 16B per lane. LDS dest = wave-uniform base + lane*16.
__device__ __forceinline__ void gload_lds16(const ushortT* g, short* lds_wave_base) {
    __builtin_amdgcn_global_load_lds(
        (const __attribute__((address_space(1))) unsigned int*)g,
        (__attribute__((address_space(3))) unsigned int*)lds_wave_base,
        16, 0, 0);
}

// ---------------------------------------------------------------------------
// One-shot fp32 -> bf16 conversion of x, Wq, Wk, Wv, Wo (fused, vectorized).
// ---------------------------------------------------------------------------
__global__ __launch_bounds__(256) void cvt_all(
    const float* __restrict__ x,  const float* __restrict__ wq,
    const float* __restrict__ wk, const float* __restrict__ wv,
    const float* __restrict__ wo,
    ushortT* __restrict__ xb,  ushortT* __restrict__ wqb,
    ushortT* __restrict__ wkb, ushortT* __restrict__ wvb,
    ushortT* __restrict__ wob)
{
    const size_t XC = QKV_ELEMS / 8;   // 1048576 chunks
    const size_t WC = W_ELEMS / 8;     // 524288 chunks
    size_t c = (size_t)blockIdx.x * 256 + threadIdx.x;
    const float* s; ushortT* d;
    if (c < XC)              { s = x;  d = xb;  }
    else if ((c -= XC) < WC) { s = wq; d = wqb; }
    else if ((c -= WC) < WC) { s = wk; d = wkb; }
    else if ((c -= WC) < WC) { s = wv; d = wvb; }
    else     { c -= WC;        s = wo; d = wob; }
    const float* f = s + c * 8;
    floatx4 a = *(const floatx4*)f;
    floatx4 b = *(const floatx4*)(f + 4);
    short8 r;
    r[0] = (short)f2bf(a.x); r[1] = (short)f2bf(a.y);
    r[2] = (short)f2bf(a.z); r[3] = (short)f2bf(a.w);
    r[4] = (short)f2bf(b.x); r[5] = (short)f2bf(b.y);
    r[6] = (short)f2bf(b.z); r[7] = (short)f2bf(b.w);
    *(short8*)(d + c * 8) = r;
}

// ---------------------------------------------------------------------------
// sin/cos table: tbl[(t*64+d)*2] = sin(t*theta[d]), +1 = cos.  1 MB, L2-fit.
// Computed ONCE (131K trig pairs) instead of per-consumer (16.8M -- the R8
// regression, confirmed fixed by R9). Overlays dead wvb after the QKV gemm.
// ---------------------------------------------------------------------------
__global__ __launch_bounds__(256) void sincos_kernel(
    float* __restrict__ tbl, const float* __restrict__ theta)
{
    const int p = blockIdx.x * 256 + threadIdx.x;   // 0..131071
    const int t = p >> 6, d = p & 63;
    const float ang = (float)t * theta[d];
    tbl[2 * p]     = sinf(ang);
    tbl[2 * p + 1] = cosf(ang);
}

// ---------------------------------------------------------------------------
// m97-structure bf16 GEMM (R4/R6/R7-verified, 792 TF, VGPR 72):
// C[M x 2048] = A @ W^T (+bias). 128x128 tile, 4 waves 2x2, BK=32.
// Linear [128][32] LDS filled by global_load_lds width-16. Plain row-major
// epilogue ONLY -- the R8/R9 fused V-frag epilogue cost +41 us in-gemm
// (write-allocate FETCH +61 MB, VGPR 72->112): reverted.
// ---------------------------------------------------------------------------
template<bool OUTF32>
__global__ __launch_bounds__(256) void gemm_bt(
    const ushortT* __restrict__ A,
    const ushortT* __restrict__ W0, const ushortT* __restrict__ W1,
    const ushortT* __restrict__ W2,
    void* C0, void* C1, void* C2, const float* __restrict__ bias)
{
    __shared__ short As[128 * 32];
    __shared__ short Bs[128 * 32];

    const int z = blockIdx.z;
    const ushortT* W = (z == 0) ? W0 : (z == 1 ? W1 : W2);
    void* C = (z == 0) ? C0 : (z == 1 ? C1 : C2);

    const int tid  = threadIdx.x;
    const int wave = tid >> 6;
    const int lane = tid & 63;
    const int lr   = lane & 15;
    const int quad = lane >> 4;
    const int wm   = (wave & 1) * 64;
    const int wn   = (wave >> 1) * 64;

    const int blockM = blockIdx.y * 128;
    const int blockN = blockIdx.x * 128;

    const int srow = tid >> 2;          // staging row 0..63 (+64 chunk 1)
    const int scol = (tid & 3) * 8;
    const ushortT* ag = A + (size_t)(blockM + srow) * D_MODEL + scol;
    const ushortT* wg = W + (size_t)(blockN + srow) * D_MODEL + scol;
    short* al = As + wave * 512;        // wave-uniform LDS base
    short* bl = Bs + wave * 512;

    floatx4 acc[4][4];
    #pragma unroll
    for (int i = 0; i < 4; i++)
        #pragma unroll
        for (int j = 0; j < 4; j++) acc[i][j] = (floatx4){0.f, 0.f, 0.f, 0.f};

    for (int kk = 0; kk < D_MODEL; kk += 32) {
        gload_lds16(ag + kk,                 al);
        gload_lds16(ag + kk + 64 * D_MODEL,  al + 64 * 32);
        gload_lds16(wg + kk,                 bl);
        gload_lds16(wg + kk + 64 * D_MODEL,  bl + 64 * 32);
        __syncthreads();

        short8 af[4], bf[4];
        #pragma unroll
        for (int s = 0; s < 4; s++) {
            af[s] = *(const short8*)&As[(wm + s * 16 + lr) * 32 + quad * 8];
            bf[s] = *(const short8*)&Bs[(wn + s * 16 + lr) * 32 + quad * 8];
        }
        #pragma unroll
        for (int sm = 0; sm < 4; sm++)
            #pragma unroll
            for (int sn = 0; sn < 4; sn++)
                acc[sm][sn] = __builtin_amdgcn_mfma_f32_16x16x32_bf16(
                    af[sm], bf[sn], acc[sm][sn], 0, 0, 0);
        __syncthreads();
    }

    #pragma unroll
    for (int sm = 0; sm < 4; sm++) {
        const int row = blockM + wm + sm * 16 + quad * 4;
        #pragma unroll
        for (int sn = 0; sn < 4; sn++) {
            const int col = blockN + wn + sn * 16 + lr;
            const float bval = bias ? bias[col] : 0.f;
            #pragma unroll
            for (int rr = 0; rr < 4; rr++) {
                const float val = acc[sm][sn][rr] + bval;
                if constexpr (OUTF32)
                    ((float*)C)[(size_t)(row + rr) * D_MODEL + col] = val;
                else
                    ((ushortT*)C)[(size_t)(row + rr) * D_MODEL + col] = f2bf(val);
            }
        }
    }
}

// ---------------------------------------------------------------------------
// K fragment pre-pack WITH FUSED RoPE (table-driven, R9-verified):
// kf[((bh*128 + kt16)*4 + ks)*512 + lane*8 + j]
//   = rope(K)[b, t = kt16*16 + lr, h, d = ks*32 + quad*8 + j]
// ---------------------------------------------------------------------------
__global__ __launch_bounds__(256) void kpack_kernel(
    const ushortT* __restrict__ k, ushortT* __restrict__ kf,
    const float* __restrict__ tbl)
{
    const int kt16 = blockIdx.x;     // 0..127
    const int bh   = blockIdx.y;     // 0..31
    const int b = bh >> 4, h = bh & 15;
    const int tid = threadIdx.x;
    const int ks = tid >> 6, lane = tid & 63;
    const int lr = lane & 15, quad = lane >> 4;

    const int t   = kt16 * 16 + lr;
    const int d0  = ks * 32 + quad * 8;
    const int dd0 = d0 & 63;
    const ushortT* src = k + (size_t)(b * SEQ + t) * D_MODEL + h * HEAD_DIM;
    short8 a  = *(const short8*)(src + 2 * dd0);
    short8 b8 = *(const short8*)(src + 2 * dd0 + 8);
    const float* tb = tbl + 2 * ((size_t)t * 64 + dd0);

    short8 v;
    #pragma unroll
    for (int j = 0; j < 8; j++) {
        const float ve = bf2f((ushortT)(j < 4 ? a[2 * j]     : b8[2 * j - 8]));
        const float vo = bf2f((ushortT)(j < 4 ? a[2 * j + 1] : b8[2 * j - 7]));
        const float s = tb[2 * j], c = tb[2 * j + 1];
        v[j] = (short)f2bf((d0 < 64) ? (ve * c - vo * s) : (ve * s + vo * c));
    }
    *(short8*)(kf + ((size_t)(bh * 128 + kt16) * 4 + ks) * 512 + lane * 8) = v;
}

// ---------------------------------------------------------------------------
// V fragment pre-pack (fused transpose, R4-verified):
// vf[((bh*8 + rt)*64 + ct)*512 + lane*8 + j] = V[b, t = ct*32+quad*8+j, h, d = rt*16+lr]
// ---------------------------------------------------------------------------
__global__ __launch_bounds__(256) void vpack_kernel(
    const ushortT* __restrict__ v, ushortT* __restrict__ vf)
{
    __shared__ ushortT tile[32][136];   // [t][d], padded
    const int ct = blockIdx.x;          // 0..63 (t / 32)
    const int bh = blockIdx.y;
    const int b = bh >> 4, h = bh & 15;
    const int tid = threadIdx.x;

    const int tt = tid >> 3;            // 0..31
    const int dc = (tid & 7) * 16;
    const ushortT* src = v + (size_t)(b * SEQ + ct * 32 + tt) * D_MODEL + h * HEAD_DIM + dc;
    *(short8*)&tile[tt][dc]     = *(const short8*)src;
    *(short8*)&tile[tt][dc + 8] = *(const short8*)(src + 8);
    __syncthreads();

    const int w = tid >> 6, lane = tid & 63;
    const int lr = lane & 15, quad = lane >> 4;
    #pragma unroll
    for (int p = 0; p < 2; p++) {
        const int rt = w + p * 4;       // 0..7
        short8 out;
        #pragma unroll
        for (int j = 0; j < 8; j++)
            out[j] = (short)tile[quad * 8 + j][rt * 16 + lr];
        *(short8*)(vf + ((size_t)(bh * 8 + rt) * 64 + ct) * 512 + lane * 8) = out;
    }
}

// ---------------------------------------------------------------------------
// MFMA flash attention (R7-verified structure: double-buffered LDS K/V,
// max-free softmax, ones-MFMA row sums) with table-driven fused RoPE-Q (R9).
// XCD remap: xcd = lid&7 owns heads {xcd, xcd+8, xcd+16, xcd+24}.
// ---------------------------------------------------------------------------
__global__ __launch_bounds__(256) void flash_attn2(
    const ushortT* __restrict__ q, const ushortT* __restrict__ kf,
    const ushortT* __restrict__ vf, ushortT* __restrict__ ctx,
    const float* __restrict__ tbl)
{
    __shared__ short Kt[2][16 * 512];    // 2 x 16 KB
    __shared__ short Vt[2][16 * 512];    // 2 x 16 KB
    __shared__ short Pl[4][16][72];      // per-wave P transpose buffer (9.2 KB)

    const unsigned lid = blockIdx.x;     // 0..511
    const int xcd  = lid & 7;
    const int slot = lid >> 3;           // 0..63
    const int ih   = slot >> 4;          // 0..3
    const int qtb  = slot & 15;          // 0..15
    const int bh   = (ih << 3) | xcd;    // head group pinned to one XCD

    const int b = bh >> 4, h = bh & 15;
    const size_t base = (size_t)b * SEQ * D_MODEL + h * HEAD_DIM;
    const size_t kfb = (size_t)bh * 128 * 4 * 512;
    const size_t vfb = (size_t)bh * 8 * 64 * 512;
    const int tid = threadIdx.x;
    const int w = tid >> 6, lane = tid & 63;
    const int lr = lane & 15, quad = lane >> 4;
    short* myP = &Pl[w][0][0];

    // constant all-ones bf16 B-frag for the row-sum MFMA
    short8 onesf;
    #pragma unroll
    for (int j = 0; j < 8; j++) onesf[j] = (short)0x3F80;   // bf16 1.0

    // stage k-tile kt0 into buffer buf (8 gload_lds16 per thread)
    auto stage_tile = [&](int kt0, int buf) {
        const ushortT* ksrc = kf + kfb + (size_t)kt0 * 128;
        #pragma unroll
        for (int c = 0; c < 4; c++)
            gload_lds16(ksrc + c * 2048 + tid * 8, &Kt[buf][c * 2048 + w * 512]);
        #pragma unroll
        for (int c = 0; c < 4; c++) {
            const int e    = c * 2048 + tid * 8;
            const int dsub = e >> 10;
            const int rem  = e & 1023;
            const ushortT* vsrc = vf + vfb +
                ((size_t)dsub * 64 + (kt0 >> 5) + (rem >> 9)) * 512 + (rem & 511);
            gload_lds16(vsrc, &Vt[buf][c * 2048 + w * 512]);
        }
    };

    for (int pass = 0; pass < 2; pass++) {
        const int qt = (pass == 0) ? qtb : (SEQ / 64 - 1 - qtb);
        const int q0 = qt * 64 + w * 16;

        // Q A-frags: table-driven RoPE + 1/sqrt(HD), single bf16 rounding
        short8 Qf[4];
        {
            const ushortT* qrow = q + base + (size_t)(q0 + lr) * D_MODEL;
            const float* trow = tbl + 2 * ((size_t)(q0 + lr) * 64);
            #pragma unroll
            for (int ks = 0; ks < 4; ks++) {
                const int d0  = ks * 32 + quad * 8;
                const int dd0 = d0 & 63;
                short8 a  = *(const short8*)(qrow + 2 * dd0);
                short8 b8 = *(const short8*)(qrow + 2 * dd0 + 8);
                const float* tb = trow + 2 * dd0;
                #pragma unroll
                for (int j = 0; j < 8; j++) {
                    const float ve = bf2f((ushortT)(j < 4 ? a[2 * j]     : b8[2 * j - 8]));
                    const float vo = bf2f((ushortT)(j < 4 ? a[2 * j + 1] : b8[2 * j - 7]));
                    const float s = tb[2 * j], c = tb[2 * j + 1];
                    const float r = (d0 < 64) ? (ve * c - vo * s) : (ve * s + vo * c);
                    Qf[ks][j] = (short)f2bf(r * 0.08838834764831845f);
                }
            }
        }

        floatx4 Of[8];
        #pragma unroll
        for (int i = 0; i < 8; i++) Of[i] = (floatx4){0.f, 0.f, 0.f, 0.f};
        floatx4 lacc = (floatx4){0.f, 0.f, 0.f, 0.f};   // row sums via ones-MFMA

        // prologue: stage tile 0, certify, publish
        stage_tile(0, 0);
        asm volatile("s_waitcnt vmcnt(0)" ::: "memory");
        __builtin_amdgcn_s_barrier();
        asm volatile("" ::: "memory");

        const int ntiles = qt + 1;
        for (int t = 0; t < ntiles; ++t) {
            const int buf = t & 1;
            const int kt0 = t * 64;

            // --- S = Q K^T from LDS K frags ---
            floatx4 Sf[4];
            #pragma unroll
            for (int sub = 0; sub < 4; sub++) {
                floatx4 acc = {0.f, 0.f, 0.f, 0.f};
                #pragma unroll
                for (int ks = 0; ks < 4; ks++) {
                    short8 Kf_ = *(const short8*)(&Kt[buf][(sub * 4 + ks) * 512 + lane * 8]);
                    acc = __builtin_amdgcn_mfma_f32_16x16x32_bf16(Qf[ks], Kf_, acc, 0, 0, 0);
                }
                Sf[sub] = acc;
            }

            // --- causal mask (diagonal tile only) ---
            if (kt0 == qt * 64) {
                #pragma unroll
                for (int sub = 0; sub < 4; sub++) {
                    const int ktg = kt0 + sub * 16 + lr;
                    #pragma unroll
                    for (int i = 0; i < 4; i++)
                        if (ktg > q0 + quad * 4 + i) Sf[sub][i] = -1e30f;
                }
            }

            // --- max-free softmax: P = exp(min(S, 60)), write to P buffer ---
            #pragma unroll
            for (int sub = 0; sub < 4; sub++) {
                #pragma unroll
                for (int i = 0; i < 4; i++) {
                    const float p = __expf(fminf(Sf[sub][i], 60.f));
                    myP[(quad * 4 + i) * 72 + sub * 16 + lr] = (short)f2bf(p);
                }
            }

            // --- V frags into regs (issued now; covers the P-write latency) ---
            short8 Vr[16];
            #pragma unroll
            for (int dsub = 0; dsub < 8; dsub++) {
                Vr[2 * dsub]     = *(const short8*)(&Vt[buf][dsub * 1024 + lane * 8]);
                Vr[2 * dsub + 1] = *(const short8*)(&Vt[buf][dsub * 1024 + 512 + lane * 8]);
            }

            // --- issue next tile's staging (hides under PV) ---
            if (t + 1 < ntiles) stage_tile((t + 1) * 64, buf ^ 1);

            // --- P: C-layout -> A-layout via wave-private LDS ---
            asm volatile("s_waitcnt lgkmcnt(0)" ::: "memory");
            short8 Pf0 = *(const short8*)(myP + lr * 72 + quad * 8);
            short8 Pf1 = *(const short8*)(myP + lr * 72 + 32 + quad * 8);

            // --- row sums: lacc += P . 1 (two ones-MFMAs) ---
            lacc = __builtin_amdgcn_mfma_f32_16x16x32_bf16(Pf0, onesf, lacc, 0, 0, 0);
            lacc = __builtin_amdgcn_mfma_f32_16x16x32_bf16(Pf1, onesf, lacc, 0, 0, 0);

            // --- O += P V (V already in registers) ---
            #pragma unroll
            for (int dsub = 0; dsub < 8; dsub++) {
                Of[dsub] = __builtin_amdgcn_mfma_f32_16x16x32_bf16(
                    Pf0, Vr[2 * dsub], Of[dsub], 0, 0, 0);
                Of[dsub] = __builtin_amdgcn_mfma_f32_16x16x32_bf16(
                    Pf1, Vr[2 * dsub + 1], Of[dsub], 0, 0, 0);
            }

            // --- tile boundary: certify own staging loads, publish ---
            asm volatile("s_waitcnt vmcnt(0)" ::: "memory");
            __builtin_amdgcn_s_barrier();
            asm volatile("" ::: "memory");
        }

        // --- epilogue ---
        float inv[4];
        #pragma unroll
        for (int i = 0; i < 4; i++) inv[i] = 1.f / lacc[i];
        #pragma unroll
        for (int dsub = 0; dsub < 8; dsub++)
            #pragma unroll
            for (int i = 0; i < 4; i++)
                ctx[base + (size_t)(q0 + quad * 4 + i) * D_MODEL + dsub * 16 + lr] =
                    f2bf(Of[dsub][i] * inv[i]);
    }
}

// ---------------------------------------------------------------------------
extern "C" void kernel_launch(void* const* d_in, const int* in_sizes, int n_in,
                              void* d_out, int out_size, void* d_ws, size_t ws_size,
                              hipStream_t stream) {
    const float* x     = (const float*)d_in[0];
    const float* Wq    = (const float*)d_in[1];
    const float* Wk    = (const float*)d_in[2];
    const float* Wv    = (const float*)d_in[3];
    const float* Wo    = (const float*)d_in[4];
    const float* bo    = (const float*)d_in[5];
    const float* theta = (const float*)d_in[6];

    // Workspace (shorts), total 96 MiB (R7 scheme + tbl overlay):
    //   qb | kb | vb | kfbp(/xb) | wqb | wkb | wvb | wob
    // kb reused as vf after kpack; vb reused as ctx after vpack;
    // tbl overlays wvb (dead after QKV gemm).
    ushortT* ws  = (ushortT*)d_ws;
    ushortT* qb   = ws;                      // Q (bf16, raw; rope fused in attn)
    ushortT* kb   = ws + QKV_ELEMS;          // K raw; becomes vf after kpack
    ushortT* vb   = ws + 2 * QKV_ELEMS;      // V row-major; becomes ctx
    ushortT* kfbp = ws + 3 * QKV_ELEMS;      // K frags (xb before kpack)
    ushortT* xb   = kfbp;                    // bf16 x (dead after QKV gemm)
    ushortT* wqb  = ws + 4 * QKV_ELEMS;      // bf16 weights
    ushortT* wkb  = wqb + W_ELEMS;
    ushortT* wvb  = wkb + W_ELEMS;
    ushortT* wob  = wvb + W_ELEMS;
    float*   tbl  = (float*)wvb;             // overlays wvb after QKV gemm

    // 0. fp32 -> bf16 one-shot conversion of x and all weights
    cvt_all<<<dim3((unsigned)((QKV_ELEMS / 8 + 4 * (W_ELEMS / 8)) / 256)), 256, 0, stream>>>(
        x, Wq, Wk, Wv, Wo, xb, wqb, wkb, wvb, wob);

    // 1. QKV projections (bf16 in, bf16 out), R7-verified plain epilogue
    gemm_bt<false><<<dim3(D_MODEL / 128, M_TOK / 128, 3), 256, 0, stream>>>(
        xb, wqb, wkb, wvb, qb, kb, vb, nullptr);

    // 2. sin/cos table (131K pairs, once) -> tbl (overlays dead wvb)
    sincos_kernel<<<dim3(SEQ * 64 / 256), 256, 0, stream>>>(tbl, theta);

    // 3. K fragment pack with table-driven RoPE: kb -> kfbp (overlays dead xb)
    kpack_kernel<<<dim3(SEQ / 16, BATCH * NUM_HEADS), 256, 0, stream>>>(kb, kfbp, tbl);

    // 4. V fragment pack (fused transpose): vb -> vf (overlays dead kb)
    vpack_kernel<<<dim3(SEQ / 32, BATCH * NUM_HEADS), 256, 0, stream>>>(vb, kb);

    // 5. Flash attention (table-driven RoPE-Q, max-free softmax) -> ctx (vb)
    flash_attn2<<<dim3(512), 256, 0, stream>>>(qb, kfbp, kb, vb, tbl);

    // 6. Output projection + bias (bf16 in, fp32 out)
    gemm_bt<true><<<dim3(D_MODEL / 128, M_TOK / 128, 1), 256, 0, stream>>>(
        vb, wob, wob, wob, d_out, d_out, d_out, bo);
}